// Round 2
// baseline (119.555 us; speedup 1.0000x reference)
//
#include <hip/hip_runtime.h>
#include <hip/hip_bf16.h>

// Problem: N=8, L=S=1024, C=256, H=8, D=32
// out = (v1 * softmax_S(q k^T / sqrt(D)) v2) @ Wp^T + bp
// Pipeline: prep (add+bf16) -> 4 projections (MFMA GEMM) -> fused attn -> out GEMM

typedef __bf16 bf16_t;
using bf16x8 = __attribute__((ext_vector_type(8))) __bf16;
using f32x4  = __attribute__((ext_vector_type(4))) float;

#define NB 8
#define LL 1024
#define SS 1024
#define CC 256
#define HH 8
#define DD 32
#define MTOK (NB * LL)   // 8192 tokens for both L-side and S-side

// 1/sqrt(D) * log2(e): softmax done in exp2 space, folded into Q at proj time
#define QSCALE (0.17677669529663688f * 1.4426950408889634f)

static __device__ __forceinline__ f32x4 mfma16(bf16x8 a, bf16x8 b, f32x4 c) {
  return __builtin_amdgcn_mfma_f32_16x16x32_bf16(a, b, c, 0, 0, 0);
}

// ---------------------------------------------------------------------------
// Kernel 1: xq = bf16(x + xe), sk = bf16(s1 + se), plus bf16 copies of weights
// ---------------------------------------------------------------------------
__global__ __launch_bounds__(256) void prep_kernel(
    const float* __restrict__ x, const float* __restrict__ xe,
    const float* __restrict__ s1, const float* __restrict__ se,
    const float* __restrict__ wq, const float* __restrict__ wk,
    const float* __restrict__ wv, const float* __restrict__ wp,
    bf16_t* __restrict__ XQ, bf16_t* __restrict__ SK, bf16_t* __restrict__ Wall) {
  const int TOK4 = (MTOK * CC) / 4;  // 524288 float4 per token tensor
  const int W4   = (CC * CC) / 4;    // 16384 float4 per weight matrix
  int i = blockIdx.x * 256 + threadIdx.x;
  const int stride = gridDim.x * 256;
  const int total = 2 * TOK4 + 4 * W4;
  for (; i < total; i += stride) {
    const float4* pa;
    const float4* pb = nullptr;
    bf16_t* o;
    int j;
    if (i < TOK4) {
      pa = (const float4*)x; pb = (const float4*)xe; o = XQ; j = i;
    } else if (i < 2 * TOK4) {
      pa = (const float4*)s1; pb = (const float4*)se; o = SK; j = i - TOK4;
    } else {
      int wi = i - 2 * TOK4;
      int w = wi >> 14;          // / W4
      j = wi & (W4 - 1);
      pa = (const float4*)(w == 0 ? wq : w == 1 ? wk : w == 2 ? wv : wp);
      o = Wall + (size_t)w * CC * CC;
    }
    float4 va = pa[j];
    if (pb) {
      float4 vb = pb[j];
      va.x += vb.x; va.y += vb.y; va.z += vb.z; va.w += vb.w;
    }
    bf16_t t4[4] __attribute__((aligned(8))) = {
        (bf16_t)va.x, (bf16_t)va.y, (bf16_t)va.z, (bf16_t)va.w};
    *(uint2*)(o + 4 * (size_t)j) = *(const uint2*)t4;
  }
}

// ---------------------------------------------------------------------------
// Kernel 2: projections (NT GEMM).  z=0: Q (pre-scaled by QSCALE), z=1: K,
// z=2: V1, z=3: V2T stored transposed per head [n][h][d][s].
// ---------------------------------------------------------------------------
__global__ __launch_bounds__(256) void proj_kernel(
    const bf16_t* __restrict__ XQ, const bf16_t* __restrict__ SK,
    const bf16_t* __restrict__ Wall,
    bf16_t* __restrict__ Qw, bf16_t* __restrict__ Kw,
    bf16_t* __restrict__ V1w, bf16_t* __restrict__ V2T) {
  const int lane = threadIdx.x & 63;
  const int wid = threadIdx.x >> 6;
  const int wm = wid >> 1, wn = wid & 1;
  const int r = lane & 15, g = lane >> 4;
  const int bm = blockIdx.x * 64, bn = blockIdx.y * 64;
  const int z = blockIdx.z;

  const bf16_t* A = (z == 1 || z == 3) ? SK : XQ;
  const bf16_t* W = Wall + (size_t)(z == 0 ? 0 : z == 1 ? 1 : 2) * CC * CC;

  const int row_a0 = bm + wm * 32;
  const int col_b0 = bn + wn * 32;

  f32x4 acc[2][2] = {};
#pragma unroll
  for (int k0 = 0; k0 < CC; k0 += 32) {
    bf16x8 a0 = *(const bf16x8*)(A + (size_t)(row_a0 + r) * CC + k0 + g * 8);
    bf16x8 a1 = *(const bf16x8*)(A + (size_t)(row_a0 + 16 + r) * CC + k0 + g * 8);
    bf16x8 b0 = *(const bf16x8*)(W + (size_t)(col_b0 + r) * CC + k0 + g * 8);
    bf16x8 b1 = *(const bf16x8*)(W + (size_t)(col_b0 + 16 + r) * CC + k0 + g * 8);
    acc[0][0] = mfma16(a0, b0, acc[0][0]);
    acc[0][1] = mfma16(a0, b1, acc[0][1]);
    acc[1][0] = mfma16(a1, b0, acc[1][0]);
    acc[1][1] = mfma16(a1, b1, acc[1][1]);
  }

  const float sc = (z == 0) ? QSCALE : 1.f;
  bf16_t* O = (z == 0) ? Qw : (z == 1) ? Kw : V1w;
#pragma unroll
  for (int i = 0; i < 2; ++i) {
#pragma unroll
    for (int j = 0; j < 2; ++j) {
      const int row_base = row_a0 + i * 16 + g * 4;
      const int col = col_b0 + j * 16 + r;
      if (z < 3) {
#pragma unroll
        for (int t = 0; t < 4; ++t)
          O[(size_t)(row_base + t) * CC + col] = (bf16_t)(acc[i][j][t] * sc);
      } else {
        // transposed per-head store: V2T[((n*H + h)*D + d)][s]
        const int n = row_base >> 10;
        const int s = row_base & (SS - 1);
        const int h = col >> 5;
        const int d = col & (DD - 1);
        bf16_t t4[4] __attribute__((aligned(8)));
#pragma unroll
        for (int t = 0; t < 4; ++t) t4[t] = (bf16_t)acc[i][j][t];
        *(uint2*)(V2T + ((size_t)((n * HH + h) * DD + d)) * SS + s) =
            *(const uint2*)t4;
      }
    }
  }
}

// ---------------------------------------------------------------------------
// Kernel 3: fused flash attention + v1 gating.
// Grid (L/16, H, N) = 4096 blocks, 4 waves/WG. Each wave owns the SAME 16
// L-rows but a DISJOINT S-range of 256 (flash-decoding style split), merged
// through LDS at the end.
// Swapped QK^T: P^T = mfma(K, Q): rows = S, col(lane&15) = L -> online
// softmax stats are per L-column, reduced with 2 shfl_xor (16,32).
// Swapped PV:  O^T = mfma(V2T, P^T): rows = D, col(lane&15) = L -> the
// rescale factor / 1/l are LANE-LOCAL (no shuffle broadcasts).
// ---------------------------------------------------------------------------
__global__ __launch_bounds__(256) void attn_kernel(
    const bf16_t* __restrict__ Qw, const bf16_t* __restrict__ Kw,
    const bf16_t* __restrict__ V1w, const bf16_t* __restrict__ V2T,
    bf16_t* __restrict__ MSG) {
  __shared__ bf16_t p_lds[4][16][72];   // per-wave P^T staging [l][s], 9.2 KB
  __shared__ float oslot[4][16][40];    // per-wave O^T partial [l][d], 10.2 KB
  __shared__ float ml[4][2][16];        // per-wave m,l per L-column

  const int lane = threadIdx.x & 63;
  const int wid = threadIdx.x >> 6;
  const int r = lane & 15, g = lane >> 4;
  const int h = blockIdx.y;
  const int n = blockIdx.z;
  const int l0 = blockIdx.x * 16;
  const size_t tokQ = (size_t)n * LL + l0;

  // Q fragment (B-operand of swapped QK^T); Q is pre-scaled by QSCALE
  const bf16x8 qf = *(const bf16x8*)(Qw + (tokQ + r) * CC + h * DD + g * 8);
  const bf16_t* Kb = Kw + ((size_t)n * SS) * CC + h * DD;
  const bf16_t* Vt = V2T + ((size_t)(n * HH + h)) * DD * SS;

  float m_run = -1e30f;
  float l_run = 0.f;
  f32x4 o0 = {0.f, 0.f, 0.f, 0.f};   // O^T rows d = g*4+reg, col l = r
  f32x4 o1 = {0.f, 0.f, 0.f, 0.f};   // O^T rows d = 16+g*4+reg
  const f32x4 zero = {0.f, 0.f, 0.f, 0.f};

  const int sbase = wid * (SS / 4);
  for (int c = 0; c < 4; ++c) {
    const int s0 = sbase + c * 64;
    // ---- QK^T for a 64-wide S chunk (4 independent MFMAs)
    bf16x8 kf0 = *(const bf16x8*)(Kb + (size_t)(s0 + r) * CC + g * 8);
    bf16x8 kf1 = *(const bf16x8*)(Kb + (size_t)(s0 + 16 + r) * CC + g * 8);
    bf16x8 kf2 = *(const bf16x8*)(Kb + (size_t)(s0 + 32 + r) * CC + g * 8);
    bf16x8 kf3 = *(const bf16x8*)(Kb + (size_t)(s0 + 48 + r) * CC + g * 8);
    f32x4 pt0 = mfma16(kf0, qf, zero);  // s rows s0+g*4+reg
    f32x4 pt1 = mfma16(kf1, qf, zero);
    f32x4 pt2 = mfma16(kf2, qf, zero);
    f32x4 pt3 = mfma16(kf3, qf, zero);

    // ---- online softmax stats (exp2 space, scale already in Q)
    float mx = fmaxf(fmaxf(fmaxf(pt0[0], pt0[1]), fmaxf(pt0[2], pt0[3])),
                     fmaxf(fmaxf(pt1[0], pt1[1]), fmaxf(pt1[2], pt1[3])));
    mx = fmaxf(mx, fmaxf(fmaxf(fmaxf(pt2[0], pt2[1]), fmaxf(pt2[2], pt2[3])),
                         fmaxf(fmaxf(pt3[0], pt3[1]), fmaxf(pt3[2], pt3[3]))));
    mx = fmaxf(mx, __shfl_xor(mx, 16));
    mx = fmaxf(mx, __shfl_xor(mx, 32));
    const float m_new = fmaxf(m_run, mx);
    const float fac = exp2f(m_run - m_new);

    float psum = 0.f;
    bf16_t pb[16] __attribute__((aligned(8)));
#pragma unroll
    for (int i = 0; i < 4; ++i) {
      float p0 = exp2f(pt0[i] - m_new);
      float p1 = exp2f(pt1[i] - m_new);
      float p2 = exp2f(pt2[i] - m_new);
      float p3 = exp2f(pt3[i] - m_new);
      psum += (p0 + p1) + (p2 + p3);
      pb[i] = (bf16_t)p0; pb[4 + i] = (bf16_t)p1;
      pb[8 + i] = (bf16_t)p2; pb[12 + i] = (bf16_t)p3;
    }
    psum += __shfl_xor(psum, 16);
    psum += __shfl_xor(psum, 32);
    l_run = l_run * fac + psum;
    m_run = m_new;

    // stage P^T (bf16) into LDS as [l][s_local]
    *(uint2*)&p_lds[wid][r][g * 4]      = *(const uint2*)&pb[0];
    *(uint2*)&p_lds[wid][r][16 + g * 4] = *(const uint2*)&pb[4];
    *(uint2*)&p_lds[wid][r][32 + g * 4] = *(const uint2*)&pb[8];
    *(uint2*)&p_lds[wid][r][48 + g * 4] = *(const uint2*)&pb[12];

    // rescale O^T accumulators — fac is lane-local (per l = r)
#pragma unroll
    for (int i = 0; i < 4; ++i) { o0[i] *= fac; o1[i] *= fac; }

    // ---- PV: O^T[d][l] += V2T[d][s] * P^T[s][l]
#pragma unroll
    for (int u = 0; u < 2; ++u) {
      bf16x8 pf = *(const bf16x8*)&p_lds[wid][r][32 * u + g * 8];
      bf16x8 va = *(const bf16x8*)(Vt + (size_t)r * SS + s0 + 32 * u + g * 8);
      bf16x8 vb = *(const bf16x8*)(Vt + (size_t)(16 + r) * SS + s0 + 32 * u + g * 8);
      o0 = mfma16(va, pf, o0);
      o1 = mfma16(vb, pf, o1);
    }
  }

  // ---- publish partials, merge across the 4 S-split waves
  if (lane < 16) {
    ml[wid][0][lane] = m_run;
    ml[wid][1][lane] = l_run;
  }
  *(f32x4*)&oslot[wid][r][g * 4]      = o0;
  *(f32x4*)&oslot[wid][r][16 + g * 4] = o1;
  __syncthreads();

  if (wid == 0) {
    const float m0 = ml[0][0][r], m1 = ml[1][0][r];
    const float m2 = ml[2][0][r], m3 = ml[3][0][r];
    const float M = fmaxf(fmaxf(m0, m1), fmaxf(m2, m3));
    const float f0 = exp2f(m0 - M), f1 = exp2f(m1 - M);
    const float f2 = exp2f(m2 - M), f3 = exp2f(m3 - M);
    const float lsum = f0 * ml[0][1][r] + f1 * ml[1][1][r] +
                       f2 * ml[2][1][r] + f3 * ml[3][1][r];
    const float linv = 1.f / lsum;

    f32x4 a0 = {0.f, 0.f, 0.f, 0.f}, a1 = {0.f, 0.f, 0.f, 0.f};
    const float fw[4] = {f0, f1, f2, f3};
#pragma unroll
    for (int w = 0; w < 4; ++w) {
      f32x4 s0v = *(const f32x4*)&oslot[w][r][g * 4];
      f32x4 s1v = *(const f32x4*)&oslot[w][r][16 + g * 4];
#pragma unroll
      for (int i = 0; i < 4; ++i) { a0[i] += fw[w] * s0v[i]; a1[i] += fw[w] * s1v[i]; }
    }

    // V1 gate + store: lane owns l = r, d = {g*4+i} and {16+g*4+i}
    const bf16_t* V1b = V1w + (tokQ + r) * CC + h * DD;
    bf16_t* Mb = MSG + (tokQ + r) * CC + h * DD;
    uint2 v1u0 = *(const uint2*)(V1b + g * 4);
    uint2 v1u1 = *(const uint2*)(V1b + 16 + g * 4);
    const bf16_t* v1a = (const bf16_t*)&v1u0;
    const bf16_t* v1b = (const bf16_t*)&v1u1;
    bf16_t ob0[4] __attribute__((aligned(8)));
    bf16_t ob1[4] __attribute__((aligned(8)));
#pragma unroll
    for (int i = 0; i < 4; ++i) {
      ob0[i] = (bf16_t)(a0[i] * linv * (float)v1a[i]);
      ob1[i] = (bf16_t)(a1[i] * linv * (float)v1b[i]);
    }
    *(uint2*)(Mb + g * 4) = *(const uint2*)ob0;
    *(uint2*)(Mb + 16 + g * 4) = *(const uint2*)ob1;
  }
}

// ---------------------------------------------------------------------------
// Kernel 4: out = MSG @ Wp^T + bp   (f32 output)
// ---------------------------------------------------------------------------
__global__ __launch_bounds__(256) void out_kernel(
    const bf16_t* __restrict__ MSG, const bf16_t* __restrict__ Wp,
    const float* __restrict__ bp, float* __restrict__ out) {
  const int lane = threadIdx.x & 63;
  const int wid = threadIdx.x >> 6;
  const int wm = wid >> 1, wn = wid & 1;
  const int r = lane & 15, g = lane >> 4;
  const int bm = blockIdx.x * 64, bn = blockIdx.y * 64;
  const int row_a0 = bm + wm * 32;
  const int col_b0 = bn + wn * 32;

  f32x4 acc[2][2] = {};
#pragma unroll
  for (int k0 = 0; k0 < CC; k0 += 32) {
    bf16x8 a0 = *(const bf16x8*)(MSG + (size_t)(row_a0 + r) * CC + k0 + g * 8);
    bf16x8 a1 = *(const bf16x8*)(MSG + (size_t)(row_a0 + 16 + r) * CC + k0 + g * 8);
    bf16x8 b0 = *(const bf16x8*)(Wp + (size_t)(col_b0 + r) * CC + k0 + g * 8);
    bf16x8 b1 = *(const bf16x8*)(Wp + (size_t)(col_b0 + 16 + r) * CC + k0 + g * 8);
    acc[0][0] = mfma16(a0, b0, acc[0][0]);
    acc[0][1] = mfma16(a0, b1, acc[0][1]);
    acc[1][0] = mfma16(a1, b0, acc[1][0]);
    acc[1][1] = mfma16(a1, b1, acc[1][1]);
  }
#pragma unroll
  for (int i = 0; i < 2; ++i) {
#pragma unroll
    for (int j = 0; j < 2; ++j) {
      const int row_base = row_a0 + i * 16 + g * 4;
      const int col = col_b0 + j * 16 + r;
      const float bv = bp[col];
#pragma unroll
      for (int t = 0; t < 4; ++t)
        out[(size_t)(row_base + t) * CC + col] = acc[i][j][t] + bv;
    }
  }
}

// ---------------------------------------------------------------------------
extern "C" void kernel_launch(void* const* d_in, const int* in_sizes, int n_in,
                              void* d_out, int out_size, void* d_ws,
                              size_t ws_size, hipStream_t stream) {
  const float* x  = (const float*)d_in[0];
  const float* s1 = (const float*)d_in[1];
  const float* xe = (const float*)d_in[2];
  const float* se = (const float*)d_in[3];
  const float* Wq = (const float*)d_in[4];
  const float* Wk = (const float*)d_in[5];
  const float* Wv = (const float*)d_in[6];
  const float* Wp = (const float*)d_in[7];
  const float* bp = (const float*)d_in[8];
  float* out = (float*)d_out;

  char* ws = (char*)d_ws;
  bf16_t* XQ   = (bf16_t*)(ws);                     // 4 MB  [8192][256]
  bf16_t* SK   = (bf16_t*)(ws + (4u << 20));        // 4 MB
  bf16_t* Wall = (bf16_t*)(ws + (8u << 20));        // 512 KB: Wq,Wk,Wv,Wp bf16
  bf16_t* Qw   = (bf16_t*)(ws + (9u << 20));        // 4 MB (pre-scaled)
  bf16_t* Kw   = (bf16_t*)(ws + (13u << 20));       // 4 MB
  bf16_t* V1w  = (bf16_t*)(ws + (17u << 20));       // 4 MB
  bf16_t* V2T  = (bf16_t*)(ws + (21u << 20));       // 4 MB [n][h][d][s]
  bf16_t* MSG  = (bf16_t*)(ws + (25u << 20));       // 4 MB
  bf16_t* Wpb  = Wall + 3 * CC * CC;

  prep_kernel<<<2048, 256, 0, stream>>>(x, xe, s1, se, Wq, Wk, Wv, Wp, XQ, SK,
                                        Wall);
  proj_kernel<<<dim3(MTOK / 64, CC / 64, 4), 256, 0, stream>>>(
      XQ, SK, Wall, Qw, Kw, V1w, V2T);
  attn_kernel<<<dim3(LL / 16, HH, NB), 256, 0, stream>>>(Qw, Kw, V1w, V2T, MSG);
  out_kernel<<<dim3(MTOK / 64, CC / 64, 1), 256, 0, stream>>>(MSG, Wpb, bp, out);
}